// Round 1
// baseline (16279.393 us; speedup 1.0000x reference)
//
#include <hip/hip_runtime.h>
#include <cmath>

// MultiLayerRNN: B=64, T=1024, D=256, H=512, O=256, L=2 (all fp32)
//
// Pipeline (all on `stream`, ws footprint ~137 MB):
//   1. transpose W_hh0, W_hh1 -> WT0, WT1 (coalesced scan reads)
//   2. gemm_rows<256>: A = x @ W_ih0^T + b_ih0 + b_hh0          [B*T, 512]
//   3. rnn_scan(store_seq=1): A <- out0 (in-place, 64 wgs, batch-partitioned, no inter-wg sync)
//   4. gemm_rows<512>: A <- A @ W_ih1^T + b_ih1 + b_hh1         (in-place: A-tile staged per k-tile before final write)
//   5. rnn_scan(store_seq=0): final h -> hT1
//   6. fc: out = hT1 @ W_fc^T + b_fc

#define Bdim 64
#define Tdim 1024
#define Ddim 256
#define Hdim 512
#define Odim 256

// ---------------- transpose 512x512 ----------------
__global__ __launch_bounds__(256) void transpose512(const float* __restrict__ in,
                                                    float* __restrict__ out) {
  __shared__ float tile[32][33];
  const int bx = blockIdx.x * 32, by = blockIdx.y * 32;
  const int tx = threadIdx.x, ty = threadIdx.y;  // 32 x 8
#pragma unroll
  for (int i = 0; i < 32; i += 8)
    tile[ty + i][tx] = in[(size_t)(by + ty + i) * 512 + bx + tx];
  __syncthreads();
#pragma unroll
  for (int i = 0; i < 32; i += 8)
    out[(size_t)(bx + ty + i) * 512 + by + tx] = tile[tx][ty + i];
}

// ---------------- row-blocked GEMM: C[m][n] = sum_k A[m][k]*W[n][k] + ba[n] + bb[n]
// M tiled by 64 rows/block, N = 512 fixed. Safe for C aliasing A (same 64 rows):
// every A element is staged into LDS (barrier-ordered) before any C write (C writes
// happen only in the epilogue after the last k-tile).
template <int K>
__global__ __launch_bounds__(1024) void gemm_rows(const float* A, const float* W,
                                                  const float* __restrict__ bias_a,
                                                  const float* __restrict__ bias_b,
                                                  float* C) {
  constexpr int KT = 16;
  __shared__ __align__(16) float As[64][KT];
  __shared__ __align__(16) float Ws[KT][516];  // +4 pad: conflict-free staging, 16B-aligned rows
  const int t = threadIdx.x;
  const size_t row0 = (size_t)blockIdx.x * 64;
  const int tn = t & 127;  // n-group: columns 4*tn..4*tn+3
  const int tm = t >> 7;   // rows tm*8 .. tm*8+7

  float acc[8][4];
#pragma unroll
  for (int i = 0; i < 8; ++i)
#pragma unroll
    for (int j = 0; j < 4; ++j) acc[i][j] = 0.f;

  const int r_st = t >> 4;  // 0..63
  const int k_st = t & 15;

  for (int k0 = 0; k0 < K; k0 += KT) {
    // stage A: 64 rows x 16 k
    As[r_st][k_st] = A[(row0 + r_st) * K + k0 + k_st];
    // stage W transposed: Ws[kk][n], 16 x 512
#pragma unroll
    for (int rep = 0; rep < 8; ++rep) {
      const int idx = rep * 1024 + t;
      const int n = idx >> 4;
      const int kk = idx & 15;
      Ws[kk][n] = W[(size_t)n * K + k0 + kk];
    }
    __syncthreads();
#pragma unroll
    for (int kk = 0; kk < KT; ++kk) {
      float a[8];
#pragma unroll
      for (int i = 0; i < 8; ++i) a[i] = As[tm * 8 + i][kk];  // broadcast reads
      const float4 w = *(const float4*)&Ws[kk][tn * 4];
#pragma unroll
      for (int i = 0; i < 8; ++i) {
        acc[i][0] = fmaf(a[i], w.x, acc[i][0]);
        acc[i][1] = fmaf(a[i], w.y, acc[i][1]);
        acc[i][2] = fmaf(a[i], w.z, acc[i][2]);
        acc[i][3] = fmaf(a[i], w.w, acc[i][3]);
      }
    }
    __syncthreads();
  }
  // epilogue: bias + store (coalesced float4)
  float bn[4];
#pragma unroll
  for (int j = 0; j < 4; ++j) bn[j] = bias_a[tn * 4 + j] + bias_b[tn * 4 + j];
#pragma unroll
  for (int i = 0; i < 8; ++i) {
    float4 v;
    v.x = acc[i][0] + bn[0];
    v.y = acc[i][1] + bn[1];
    v.z = acc[i][2] + bn[2];
    v.w = acc[i][3] + bn[3];
    *(float4*)&C[(row0 + tm * 8 + i) * (size_t)Hdim + tn * 4] = v;
  }
}

// ---------------- recurrent scan ----------------
// One workgroup per batch row; h lives in LDS; W_hh^T streamed from L2.
// y[j] = xw[b,t,j] + sum_k WT[k][j] * h[k];  h = tanh(y)
// store_seq: write h back over xw (produces out0 in place).
__global__ __launch_bounds__(512) void rnn_scan(float* xw,                      // [B][T][512]
                                                const float* __restrict__ WT,  // [512][512]
                                                float* __restrict__ h_final,   // [B][512] or null
                                                const int store_seq) {
  __shared__ __align__(16) float h_s[Hdim];
  __shared__ __align__(16) float red[4][Hdim];
  const int b = blockIdx.x;
  const int t = threadIdx.x;
  const int jg = t & 127;  // output group: j = 4*jg..4*jg+3
  const int ks = t >> 7;   // k-slice 0..3 -> k in [128*ks, 128*ks+128)
  h_s[t] = 0.0f;
  __syncthreads();

  float* row = xw + (size_t)b * Tdim * Hdim;
  for (int step = 0; step < Tdim; ++step, row += Hdim) {
    const float* wp = WT + (size_t)(ks * 128) * Hdim + (jg << 2);
    const float* hp = &h_s[ks * 128];
    float4 acc = make_float4(0.f, 0.f, 0.f, 0.f);
#pragma unroll 8
    for (int k = 0; k < 128; ++k) {
      const float hk = hp[k];            // LDS broadcast (wave-uniform addr)
      const float4 w = *(const float4*)wp;  // coalesced: lanes contiguous over j
      acc.x = fmaf(w.x, hk, acc.x);
      acc.y = fmaf(w.y, hk, acc.y);
      acc.z = fmaf(w.z, hk, acc.z);
      acc.w = fmaf(w.w, hk, acc.w);
      wp += Hdim;
    }
    *(float4*)&red[ks][jg << 2] = acc;
    __syncthreads();  // all h_s reads + red writes complete
    const float y = row[t] + red[0][t] + red[1][t] + red[2][t] + red[3][t];
    const float hn = tanhf(y);
    if (store_seq) row[t] = hn;
    h_s[t] = hn;
    __syncthreads();  // h_s visible before next step's reads
  }
  if (h_final != nullptr) h_final[(size_t)b * Hdim + t] = h_s[t];
}

// ---------------- final FC ----------------
__global__ __launch_bounds__(256) void fc_kernel(const float* __restrict__ h,    // [B][512]
                                                 const float* __restrict__ Wfc,  // [256][512]
                                                 const float* __restrict__ bfc,
                                                 float* __restrict__ out) {  // [B][256]
  __shared__ float hs[Hdim];
  const int b = blockIdx.x, o = threadIdx.x;
  hs[o] = h[(size_t)b * Hdim + o];
  hs[o + 256] = h[(size_t)b * Hdim + 256 + o];
  __syncthreads();
  float acc = bfc[o];
  const float* wr = Wfc + (size_t)o * Hdim;
#pragma unroll 4
  for (int k = 0; k < Hdim; k += 4) {
    const float4 w = *(const float4*)(wr + k);
    acc = fmaf(w.x, hs[k], acc);
    acc = fmaf(w.y, hs[k + 1], acc);
    acc = fmaf(w.z, hs[k + 2], acc);
    acc = fmaf(w.w, hs[k + 3], acc);
  }
  out[(size_t)b * Odim + o] = acc;
}

extern "C" void kernel_launch(void* const* d_in, const int* in_sizes, int n_in,
                              void* d_out, int out_size, void* d_ws, size_t ws_size,
                              hipStream_t stream) {
  const float* x = (const float*)d_in[0];
  const float* W_ih0 = (const float*)d_in[1];
  const float* W_hh0 = (const float*)d_in[2];
  const float* b_ih0 = (const float*)d_in[3];
  const float* b_hh0 = (const float*)d_in[4];
  const float* W_ih1 = (const float*)d_in[5];
  const float* W_hh1 = (const float*)d_in[6];
  const float* b_ih1 = (const float*)d_in[7];
  const float* b_hh1 = (const float*)d_in[8];
  const float* W_fc = (const float*)d_in[9];
  const float* b_fc = (const float*)d_in[10];
  float* out = (float*)d_out;

  float* A = (float*)d_ws;                          // B*T*H fp32 = 134 MB
  float* WT0 = A + (size_t)Bdim * Tdim * Hdim;      // 1 MB
  float* WT1 = WT0 + (size_t)Hdim * Hdim;           // 1 MB
  float* hT1 = WT1 + (size_t)Hdim * Hdim;           // 128 KB

  dim3 tb(32, 8);
  transpose512<<<dim3(16, 16), tb, 0, stream>>>(W_hh0, WT0);
  transpose512<<<dim3(16, 16), tb, 0, stream>>>(W_hh1, WT1);

  // A = x @ W_ih0^T + b_ih0 + b_hh0
  gemm_rows<Ddim><<<(Bdim * Tdim) / 64, 1024, 0, stream>>>(x, W_ih0, b_ih0, b_hh0, A);
  // A <- out0 (in place)
  rnn_scan<<<Bdim, Hdim, 0, stream>>>(A, WT0, nullptr, 1);
  // A <- A @ W_ih1^T + b_ih1 + b_hh1 (in place)
  gemm_rows<Hdim><<<(Bdim * Tdim) / 64, 1024, 0, stream>>>(A, W_ih1, b_ih1, b_hh1, A);
  // final hidden of layer 1
  rnn_scan<<<Bdim, Hdim, 0, stream>>>(A, WT1, hT1, 0);
  // out = hT1 @ W_fc^T + b_fc
  fc_kernel<<<Bdim, Odim, 0, stream>>>(hT1, W_fc, b_fc, out);
}

// Round 2
// 8865.066 us; speedup vs baseline: 1.8364x; 1.8364x over previous
//
#include <hip/hip_runtime.h>
#include <cmath>

// MultiLayerRNN: B=64, T=1024, D=256, H=512, O=256, L=2 (all fp32)
//
// R2: register-resident W_hh scan. 256 wgs = 64 batch rows x 4 hidden-quarters.
// Each wg holds its 512x128 W_hh slice in VGPRs (128 regs/thread) for the whole
// scan; per step the 4 peer wgs of a batch row exchange 128-float h-quarters via
// device-scope atomics + per-quarter seq flags (double-buffered hbuf).
// Co-residency guaranteed by hipLaunchCooperativeKernel.

#define Bdim 64
#define Tdim 1024
#define Ddim 256
#define Hdim 512
#define Odim 256

// ---------------- row-blocked GEMM: C[m][n] = sum_k A[m][k]*W[n][k] + ba[n] + bb[n]
// M tiled by 64 rows/block, N = 512 fixed. Safe for C aliasing A (same 64 rows):
// every A element is staged into LDS (barrier-ordered) before any C write.
template <int K>
__global__ __launch_bounds__(1024) void gemm_rows(const float* A, const float* W,
                                                  const float* __restrict__ bias_a,
                                                  const float* __restrict__ bias_b,
                                                  float* C) {
  constexpr int KT = 16;
  __shared__ __align__(16) float As[64][KT];
  __shared__ __align__(16) float Ws[KT][516];
  const int t = threadIdx.x;
  const size_t row0 = (size_t)blockIdx.x * 64;
  const int tn = t & 127;
  const int tm = t >> 7;

  float acc[8][4];
#pragma unroll
  for (int i = 0; i < 8; ++i)
#pragma unroll
    for (int j = 0; j < 4; ++j) acc[i][j] = 0.f;

  const int r_st = t >> 4;
  const int k_st = t & 15;

  for (int k0 = 0; k0 < K; k0 += KT) {
    As[r_st][k_st] = A[(row0 + r_st) * K + k0 + k_st];
#pragma unroll
    for (int rep = 0; rep < 8; ++rep) {
      const int idx = rep * 1024 + t;
      const int n = idx >> 4;
      const int kk = idx & 15;
      Ws[kk][n] = W[(size_t)n * K + k0 + kk];
    }
    __syncthreads();
#pragma unroll
    for (int kk = 0; kk < KT; ++kk) {
      float a[8];
#pragma unroll
      for (int i = 0; i < 8; ++i) a[i] = As[tm * 8 + i][kk];
      const float4 w = *(const float4*)&Ws[kk][tn * 4];
#pragma unroll
      for (int i = 0; i < 8; ++i) {
        acc[i][0] = fmaf(a[i], w.x, acc[i][0]);
        acc[i][1] = fmaf(a[i], w.y, acc[i][1]);
        acc[i][2] = fmaf(a[i], w.z, acc[i][2]);
        acc[i][3] = fmaf(a[i], w.w, acc[i][3]);
      }
    }
    __syncthreads();
  }
  float bn[4];
#pragma unroll
  for (int j = 0; j < 4; ++j) bn[j] = bias_a[tn * 4 + j] + bias_b[tn * 4 + j];
#pragma unroll
  for (int i = 0; i < 8; ++i) {
    float4 v;
    v.x = acc[i][0] + bn[0];
    v.y = acc[i][1] + bn[1];
    v.z = acc[i][2] + bn[2];
    v.w = acc[i][3] + bn[3];
    *(float4*)&C[(row0 + tm * 8 + i) * (size_t)Hdim + tn * 4] = v;
  }
}

// ---------------- register-resident recurrent scan ----------------
// Block bi: b = bi&63 (batch row), q = bi>>6 (hidden quarter, 128 outputs).
// Thread t: ks = t>>6 (k-slice of 64), jp = t&63 (handles 2 outputs j=2jp,2jp+1).
// W slice (2 rows x 64 k = 128 floats) lives in VGPRs for the whole scan.
__global__ __launch_bounds__(512, 2) void rnn_scan_coop(
    float* xw,                       // [B][T][512]
    const float* __restrict__ Whh,   // [512][512] row-major (j,k)
    float* hbuf,                     // [2][B][512] exchange buffers
    int* seq,                        // [B][4] sequence flags (poisoned negative)
    float* h_final,                  // [B][512] or null
    const int store_seq) {
  const int bi = blockIdx.x;
  const int b = bi & 63;
  const int q = bi >> 6;
  const int t = threadIdx.x;
  const int ks = t >> 6;   // 0..7, uniform within each wave
  const int jp = t & 63;
  const int jl0 = jp * 2;               // local output pair
  const int jg0 = q * 128 + jl0;        // global output row in W

  __shared__ __align__(16) float h_s[Hdim];
  __shared__ __align__(16) float red[8][128];

  // ---- load W slice into registers (one-time, ~256 KB/wg) ----
  float4 W0[16], W1[16];
  {
    const float4* w0p = (const float4*)(Whh + (size_t)jg0 * Hdim + ks * 64);
    const float4* w1p = (const float4*)(Whh + (size_t)(jg0 + 1) * Hdim + ks * 64);
#pragma unroll
    for (int c = 0; c < 16; ++c) {
      W0[c] = w0p[c];
      W1[c] = w1p[c];
    }
  }

  h_s[t] = 0.0f;
  __syncthreads();

  float* row = xw + (size_t)b * Tdim * Hdim;
  int* myseq = seq + b * 4;

  for (int s = 0; s < Tdim; ++s, row += Hdim) {
    // own xw slice element (epilogue input) — issue early
    float xv = 0.f;
    if (t < 128) xv = row[q * 128 + t];

    // ---- MAC: partials over this thread's k-slice, 2 outputs ----
    const float4* h4 = (const float4*)h_s + ks * 16;  // wave-uniform address
    float a0 = 0.f, a0b = 0.f, a1 = 0.f, a1b = 0.f;
#pragma unroll
    for (int c = 0; c < 16; ++c) {
      const float4 hv = h4[c];
      a0  = fmaf(W0[c].x, hv.x, a0);
      a0b = fmaf(W0[c].y, hv.y, a0b);
      a0  = fmaf(W0[c].z, hv.z, a0);
      a0b = fmaf(W0[c].w, hv.w, a0b);
      a1  = fmaf(W1[c].x, hv.x, a1);
      a1b = fmaf(W1[c].y, hv.y, a1b);
      a1  = fmaf(W1[c].z, hv.z, a1);
      a1b = fmaf(W1[c].w, hv.w, a1b);
    }
    *(float2*)&red[ks][jl0] = make_float2(a0 + a0b, a1 + a1b);
    __syncthreads();  // B1: h_s reads + red writes complete

    // ---- epilogue: reduce 8 slices, tanh, publish own quarter ----
    float* hbW = hbuf + (size_t)((s + 1) & 1) * Bdim * Hdim + b * Hdim;
    if (t < 128) {
      float y = xv;
#pragma unroll
      for (int s8 = 0; s8 < 8; ++s8) y += red[s8][t];
      const float hn = tanhf(y);
      h_s[q * 128 + t] = hn;
      __hip_atomic_store(&hbW[q * 128 + t], hn, __ATOMIC_RELAXED,
                         __HIP_MEMORY_SCOPE_AGENT);
      if (store_seq) row[q * 128 + t] = hn;
    }
    __syncthreads();  // B2: publishes issued+drained before flag

    if (t == 0)
      __hip_atomic_store(&myseq[q], s + 1, __ATOMIC_RELEASE,
                         __HIP_MEMORY_SCOPE_AGENT);
    if (t < 4 && t != q) {
      while (__hip_atomic_load(&myseq[t], __ATOMIC_RELAXED,
                               __HIP_MEMORY_SCOPE_AGENT) < s + 1) {
      }
    }
    __syncthreads();  // B3: all peer quarters posted

    // ---- pull peers' 3 quarters into h_s (L2-direct atomic loads) ----
    if (t >= 128) {
      const int idx = t - 128;            // 0..383
      const int pq = idx >> 7;            // 0..2
      const int i = idx & 127;
      const int q2 = pq + (pq >= q);      // skip own quarter
      h_s[q2 * 128 + i] = __hip_atomic_load(&hbW[q2 * 128 + i], __ATOMIC_RELAXED,
                                            __HIP_MEMORY_SCOPE_AGENT);
    }
    __syncthreads();  // B4: h_s complete for next step
  }

  if (h_final != nullptr && t < 128)
    h_final[(size_t)b * Hdim + q * 128 + t] = h_s[q * 128 + t];
}

// ---------------- final FC ----------------
__global__ __launch_bounds__(256) void fc_kernel(const float* __restrict__ h,
                                                 const float* __restrict__ Wfc,
                                                 const float* __restrict__ bfc,
                                                 float* __restrict__ out) {
  __shared__ float hs[Hdim];
  const int b = blockIdx.x, o = threadIdx.x;
  hs[o] = h[(size_t)b * Hdim + o];
  hs[o + 256] = h[(size_t)b * Hdim + 256 + o];
  __syncthreads();
  float acc = bfc[o];
  const float* wr = Wfc + (size_t)o * Hdim;
#pragma unroll 4
  for (int k = 0; k < Hdim; k += 4) {
    const float4 w = *(const float4*)(wr + k);
    acc = fmaf(w.x, hs[k], acc);
    acc = fmaf(w.y, hs[k + 1], acc);
    acc = fmaf(w.z, hs[k + 2], acc);
    acc = fmaf(w.w, hs[k + 3], acc);
  }
  out[(size_t)b * Odim + o] = acc;
}

extern "C" void kernel_launch(void* const* d_in, const int* in_sizes, int n_in,
                              void* d_out, int out_size, void* d_ws, size_t ws_size,
                              hipStream_t stream) {
  const float* x = (const float*)d_in[0];
  const float* W_ih0 = (const float*)d_in[1];
  const float* W_hh0 = (const float*)d_in[2];
  const float* b_ih0 = (const float*)d_in[3];
  const float* b_hh0 = (const float*)d_in[4];
  const float* W_ih1 = (const float*)d_in[5];
  const float* W_hh1 = (const float*)d_in[6];
  const float* b_ih1 = (const float*)d_in[7];
  const float* b_hh1 = (const float*)d_in[8];
  const float* W_fc = (const float*)d_in[9];
  const float* b_fc = (const float*)d_in[10];
  float* out = (float*)d_out;

  float* A = (float*)d_ws;                           // B*T*H fp32 = 134 MB
  float* hbuf = A + (size_t)Bdim * Tdim * Hdim;      // 2*B*H = 256 KB
  float* hT1 = hbuf + (size_t)2 * Bdim * Hdim;       // B*H = 128 KB
  int* seq0 = (int*)(hT1 + (size_t)Bdim * Hdim);     // B*4 ints
  int* seq1 = seq0 + Bdim * 4;
  // seq poisoned to 0xAAAAAAAA (negative int) by harness -> spin-safe, no init.

  // A = x @ W_ih0^T + b_ih0 + b_hh0
  gemm_rows<Ddim><<<(Bdim * Tdim) / 64, 1024, 0, stream>>>(x, W_ih0, b_ih0, b_hh0, A);

  // layer-0 scan: A <- out0 (in place)
  {
    float* xw = A;
    const float* W = W_hh0;
    float* hf = nullptr;
    int ss = 1;
    void* args[] = {&xw, (void*)&W, &hbuf, &seq0, &hf, &ss};
    hipLaunchCooperativeKernel((void*)rnn_scan_coop, dim3(Bdim * 4), dim3(512),
                               args, 0, stream);
  }

  // A <- A @ W_ih1^T + b_ih1 + b_hh1 (in place)
  gemm_rows<Hdim><<<(Bdim * Tdim) / 64, 1024, 0, stream>>>(A, W_ih1, b_ih1, b_hh1, A);

  // layer-1 scan: final hidden only
  {
    float* xw = A;
    const float* W = W_hh1;
    float* hf = hT1;
    int ss = 0;
    void* args[] = {&xw, (void*)&W, &hbuf, &seq1, &hf, &ss};
    hipLaunchCooperativeKernel((void*)rnn_scan_coop, dim3(Bdim * 4), dim3(512),
                               args, 0, stream);
  }

  // out = hT1 @ W_fc^T + b_fc
  fc_kernel<<<Bdim, Odim, 0, stream>>>(hT1, W_fc, b_fc, out);
}

// Round 3
// 3754.024 us; speedup vs baseline: 4.3365x; 2.3615x over previous
//
#include <hip/hip_runtime.h>
#include <cmath>

// MultiLayerRNN: B=64, T=1024, D=256, H=512, O=256, L=2 (all fp32)
//
// R3: register-resident W_hh scan (forced via opaque asm), self-flagged
// 8-byte (seq|float) h-exchange through agent-scope atomics. 256 wgs =
// 64 batch rows x 4 hidden-quarters, 1 wg/CU, cooperative launch.

#define Bdim 64
#define Tdim 1024
#define Ddim 256
#define Hdim 512
#define Odim 256

// ---------------- row-blocked GEMM: C[m][n] = sum_k A[m][k]*W[n][k] + ba[n] + bb[n]
// M tiled by 64 rows/block, N = 512 fixed. Safe for C aliasing A (same 64 rows):
// every A element is staged into LDS (barrier-ordered) before any C write.
template <int K>
__global__ __launch_bounds__(1024) void gemm_rows(const float* A, const float* W,
                                                  const float* __restrict__ bias_a,
                                                  const float* __restrict__ bias_b,
                                                  float* C) {
  constexpr int KT = 16;
  __shared__ __align__(16) float As[64][KT];
  __shared__ __align__(16) float Ws[KT][516];
  const int t = threadIdx.x;
  const size_t row0 = (size_t)blockIdx.x * 64;
  const int tn = t & 127;
  const int tm = t >> 7;

  float acc[8][4];
#pragma unroll
  for (int i = 0; i < 8; ++i)
#pragma unroll
    for (int j = 0; j < 4; ++j) acc[i][j] = 0.f;

  const int r_st = t >> 4;
  const int k_st = t & 15;

  for (int k0 = 0; k0 < K; k0 += KT) {
    As[r_st][k_st] = A[(row0 + r_st) * K + k0 + k_st];
#pragma unroll
    for (int rep = 0; rep < 8; ++rep) {
      const int idx = rep * 1024 + t;
      const int n = idx >> 4;
      const int kk = idx & 15;
      Ws[kk][n] = W[(size_t)n * K + k0 + kk];
    }
    __syncthreads();
#pragma unroll
    for (int kk = 0; kk < KT; ++kk) {
      float a[8];
#pragma unroll
      for (int i = 0; i < 8; ++i) a[i] = As[tm * 8 + i][kk];
      const float4 w = *(const float4*)&Ws[kk][tn * 4];
#pragma unroll
      for (int i = 0; i < 8; ++i) {
        acc[i][0] = fmaf(a[i], w.x, acc[i][0]);
        acc[i][1] = fmaf(a[i], w.y, acc[i][1]);
        acc[i][2] = fmaf(a[i], w.z, acc[i][2]);
        acc[i][3] = fmaf(a[i], w.w, acc[i][3]);
      }
    }
    __syncthreads();
  }
  float bn[4];
#pragma unroll
  for (int j = 0; j < 4; ++j) bn[j] = bias_a[tn * 4 + j] + bias_b[tn * 4 + j];
#pragma unroll
  for (int i = 0; i < 8; ++i) {
    float4 v;
    v.x = acc[i][0] + bn[0];
    v.y = acc[i][1] + bn[1];
    v.z = acc[i][2] + bn[2];
    v.w = acc[i][3] + bn[3];
    *(float4*)&C[(row0 + tm * 8 + i) * (size_t)Hdim + tn * 4] = v;
  }
}

// ---------------- register-resident recurrent scan ----------------
// Block bi: b = bi&63 (batch row), q = bi>>6 (hidden quarter, 128 outputs).
// Thread t: ks = t>>6 (k-slice of 64, wave-uniform), jp = t&63 (2 outputs).
// W slice (2 rows x 64 k = 128 floats) pinned in VGPRs via opaque asm.
// h exchange: packed (seq<<32 | float_bits) agent-scope atomics; peers poll
// the data word itself (no separate flag, no release drain).
__global__ __launch_bounds__(512, 2) void rnn_scan_coop(
    float* xw,                        // [B][T][512]
    const float* __restrict__ Whh,    // [512][512] row-major (j,k)
    unsigned long long* hbuf,         // [2][B][512] packed exchange
    float* h_final,                   // [B][512] or null
    const int store_seq) {
  const int bi = blockIdx.x;
  const int b = bi & 63;
  const int q = bi >> 6;
  const int t = threadIdx.x;
  const int ks = t >> 6;                // 0..7, uniform per wave
  const int jp = t & 63;
  const int jl0 = jp * 2;               // local output pair
  const int jg0 = q * 128 + jl0;        // global W row

  __shared__ __align__(16) float h_s[Hdim];
  __shared__ __align__(16) float red[8][128];

  // ---- load W slice and pin in registers ----
  float4 W0[16], W1[16];
  {
    const float4* w0p = (const float4*)(Whh + (size_t)jg0 * Hdim + ks * 64);
    const float4* w1p = (const float4*)(Whh + (size_t)(jg0 + 1) * Hdim + ks * 64);
#pragma unroll
    for (int c = 0; c < 16; ++c) {
      W0[c] = w0p[c];
      W1[c] = w1p[c];
    }
  }
#pragma unroll
  for (int c = 0; c < 16; ++c) {
    asm volatile("" : "+v"(W0[c].x), "+v"(W0[c].y), "+v"(W0[c].z), "+v"(W0[c].w));
    asm volatile("" : "+v"(W1[c].x), "+v"(W1[c].y), "+v"(W1[c].z), "+v"(W1[c].w));
  }

  h_s[t] = 0.0f;
  __syncthreads();

  float* row = xw + (size_t)b * Tdim * Hdim;

  for (int s = 0; s < Tdim; ++s, row += Hdim) {
    // own xw element (epilogue input) — issue early, consumed after B1
    float xv = 0.f;
    if (t < 128) xv = row[q * 128 + t];

    // ---- MAC over this thread's k-slice (wave-uniform LDS broadcasts) ----
    const float4* h4 = (const float4*)h_s + ks * 16;
    float a0 = 0.f, a0b = 0.f, a1 = 0.f, a1b = 0.f;
#pragma unroll
    for (int c = 0; c < 16; ++c) {
      const float4 hv = h4[c];
      a0  = fmaf(W0[c].x, hv.x, a0);
      a0b = fmaf(W0[c].y, hv.y, a0b);
      a0  = fmaf(W0[c].z, hv.z, a0);
      a0b = fmaf(W0[c].w, hv.w, a0b);
      a1  = fmaf(W1[c].x, hv.x, a1);
      a1b = fmaf(W1[c].y, hv.y, a1b);
      a1  = fmaf(W1[c].z, hv.z, a1);
      a1b = fmaf(W1[c].w, hv.w, a1b);
    }
    *(float2*)&red[ks][jl0] = make_float2(a0 + a0b, a1 + a1b);
    __syncthreads();  // B1: all h_s reads + red writes complete

    unsigned long long* hbW =
        hbuf + (size_t)((s + 1) & 1) * Bdim * Hdim + b * Hdim;

    if (t < 128) {
      // ---- epilogue (waves 0-1): reduce, tanh, publish own quarter ----
      float y = xv;
#pragma unroll
      for (int s8 = 0; s8 < 8; ++s8) y += red[s8][t];
      const float hn = tanhf(y);
      const unsigned long long pv =
          ((unsigned long long)(unsigned)(s + 1) << 32) |
          (unsigned long long)__float_as_uint(hn);
      __hip_atomic_store(&hbW[q * 128 + t], pv, __ATOMIC_RELAXED,
                         __HIP_MEMORY_SCOPE_AGENT);
      h_s[q * 128 + t] = hn;
      if (store_seq) row[q * 128 + t] = hn;
    } else {
      // ---- pull (waves 2-7): poll peers' self-flagged words ----
      const int idx = t - 128;         // 0..383
      const int pq = idx >> 7;         // 0..2
      const int i = idx & 127;
      const int q2 = pq + (pq >= q);   // skip own quarter
      const unsigned long long* src = &hbW[q2 * 128 + i];
      unsigned long long v;
      do {
        v = __hip_atomic_load(src, __ATOMIC_RELAXED, __HIP_MEMORY_SCOPE_AGENT);
      } while ((unsigned)(v >> 32) != (unsigned)(s + 1));
      h_s[q2 * 128 + i] = __uint_as_float((unsigned)v);
    }
    __syncthreads();  // B2: h_s complete for next step
  }

  if (h_final != nullptr && t < 128)
    h_final[(size_t)b * Hdim + q * 128 + t] = h_s[q * 128 + t];
}

// ---------------- final FC ----------------
__global__ __launch_bounds__(256) void fc_kernel(const float* __restrict__ h,
                                                 const float* __restrict__ Wfc,
                                                 const float* __restrict__ bfc,
                                                 float* __restrict__ out) {
  __shared__ float hs[Hdim];
  const int b = blockIdx.x, o = threadIdx.x;
  hs[o] = h[(size_t)b * Hdim + o];
  hs[o + 256] = h[(size_t)b * Hdim + 256 + o];
  __syncthreads();
  float acc = bfc[o];
  const float* wr = Wfc + (size_t)o * Hdim;
#pragma unroll 4
  for (int k = 0; k < Hdim; k += 4) {
    const float4 w = *(const float4*)(wr + k);
    acc = fmaf(w.x, hs[k], acc);
    acc = fmaf(w.y, hs[k + 1], acc);
    acc = fmaf(w.z, hs[k + 2], acc);
    acc = fmaf(w.w, hs[k + 3], acc);
  }
  out[(size_t)b * Odim + o] = acc;
}

extern "C" void kernel_launch(void* const* d_in, const int* in_sizes, int n_in,
                              void* d_out, int out_size, void* d_ws, size_t ws_size,
                              hipStream_t stream) {
  const float* x = (const float*)d_in[0];
  const float* W_ih0 = (const float*)d_in[1];
  const float* W_hh0 = (const float*)d_in[2];
  const float* b_ih0 = (const float*)d_in[3];
  const float* b_hh0 = (const float*)d_in[4];
  const float* W_ih1 = (const float*)d_in[5];
  const float* W_hh1 = (const float*)d_in[6];
  const float* b_ih1 = (const float*)d_in[7];
  const float* b_hh1 = (const float*)d_in[8];
  const float* W_fc = (const float*)d_in[9];
  const float* b_fc = (const float*)d_in[10];
  float* out = (float*)d_out;

  float* A = (float*)d_ws;                                  // B*T*H fp32 = 134 MB
  unsigned long long* hbuf0 =
      (unsigned long long*)(A + (size_t)Bdim * Tdim * Hdim);   // 512 KB
  unsigned long long* hbuf1 = hbuf0 + (size_t)2 * Bdim * Hdim; // 512 KB
  float* hT1 = (float*)(hbuf1 + (size_t)2 * Bdim * Hdim);      // 128 KB
  // hbuf poison (0xAA..) never matches a valid seq (exact-equality poll);
  // separate per-layer buffers avoid cross-dispatch seq collisions.

  // A = x @ W_ih0^T + b_ih0 + b_hh0
  gemm_rows<Ddim><<<(Bdim * Tdim) / 64, 1024, 0, stream>>>(x, W_ih0, b_ih0, b_hh0, A);

  // layer-0 scan: A <- out0 (in place)
  {
    float* xwp = A;
    const float* W = W_hh0;
    unsigned long long* hb = hbuf0;
    float* hf = nullptr;
    int ss = 1;
    void* args[] = {&xwp, (void*)&W, &hb, &hf, &ss};
    hipLaunchCooperativeKernel((void*)rnn_scan_coop, dim3(Bdim * 4), dim3(512),
                               args, 0, stream);
  }

  // A <- A @ W_ih1^T + b_ih1 + b_hh1 (in place)
  gemm_rows<Hdim><<<(Bdim * Tdim) / 64, 1024, 0, stream>>>(A, W_ih1, b_ih1, b_hh1, A);

  // layer-1 scan: final hidden only
  {
    float* xwp = A;
    const float* W = W_hh1;
    unsigned long long* hb = hbuf1;
    float* hf = hT1;
    int ss = 0;
    void* args[] = {&xwp, (void*)&W, &hb, &hf, &ss};
    hipLaunchCooperativeKernel((void*)rnn_scan_coop, dim3(Bdim * 4), dim3(512),
                               args, 0, stream);
  }

  // out = hT1 @ W_fc^T + b_fc
  fc_kernel<<<Bdim, Odim, 0, stream>>>(hT1, W_fc, b_fc, out);
}

// Round 4
// 3621.349 us; speedup vs baseline: 4.4954x; 1.0366x over previous
//
#include <hip/hip_runtime.h>
#include <cmath>

// MultiLayerRNN: B=64, T=1024, D=256, H=512, O=256, L=2 (all fp32)
//
// R4: single-barrier pipelined scan. 256 wgs = 64 rows x 4 quarters, W slice
// pinned in registers (AGPR-resident is fine on gfx950). Wave w owns k-slice
// [64w,64w+64): own-quarter waves gate on an LDS seq flag; peer waves poll the
// packed (seq<<32|bits) words per-wave with NO barrier between publish and
// consume. hL/red double-buffered by parity -> one __syncthreads per step.

#define Bdim 64
#define Tdim 1024
#define Ddim 256
#define Hdim 512
#define Odim 256

// ---------------- row-blocked GEMM: C[m][n] = sum_k A[m][k]*W[n][k] + ba[n] + bb[n]
template <int K>
__global__ __launch_bounds__(1024) void gemm_rows(const float* A, const float* W,
                                                  const float* __restrict__ bias_a,
                                                  const float* __restrict__ bias_b,
                                                  float* C) {
  constexpr int KT = 16;
  __shared__ __align__(16) float As[64][KT];
  __shared__ __align__(16) float Ws[KT][516];
  const int t = threadIdx.x;
  const size_t row0 = (size_t)blockIdx.x * 64;
  const int tn = t & 127;
  const int tm = t >> 7;

  float acc[8][4];
#pragma unroll
  for (int i = 0; i < 8; ++i)
#pragma unroll
    for (int j = 0; j < 4; ++j) acc[i][j] = 0.f;

  const int r_st = t >> 4;
  const int k_st = t & 15;

  for (int k0 = 0; k0 < K; k0 += KT) {
    As[r_st][k_st] = A[(row0 + r_st) * K + k0 + k_st];
#pragma unroll
    for (int rep = 0; rep < 8; ++rep) {
      const int idx = rep * 1024 + t;
      const int n = idx >> 4;
      const int kk = idx & 15;
      Ws[kk][n] = W[(size_t)n * K + k0 + kk];
    }
    __syncthreads();
#pragma unroll
    for (int kk = 0; kk < KT; ++kk) {
      float a[8];
#pragma unroll
      for (int i = 0; i < 8; ++i) a[i] = As[tm * 8 + i][kk];
      const float4 w = *(const float4*)&Ws[kk][tn * 4];
#pragma unroll
      for (int i = 0; i < 8; ++i) {
        acc[i][0] = fmaf(a[i], w.x, acc[i][0]);
        acc[i][1] = fmaf(a[i], w.y, acc[i][1]);
        acc[i][2] = fmaf(a[i], w.z, acc[i][2]);
        acc[i][3] = fmaf(a[i], w.w, acc[i][3]);
      }
    }
    __syncthreads();
  }
  float bn[4];
#pragma unroll
  for (int j = 0; j < 4; ++j) bn[j] = bias_a[tn * 4 + j] + bias_b[tn * 4 + j];
#pragma unroll
  for (int i = 0; i < 8; ++i) {
    float4 v;
    v.x = acc[i][0] + bn[0];
    v.y = acc[i][1] + bn[1];
    v.z = acc[i][2] + bn[2];
    v.w = acc[i][3] + bn[3];
    *(float4*)&C[(row0 + tm * 8 + i) * (size_t)Hdim + tn * 4] = v;
  }
}

// ---------------- pipelined register-resident recurrent scan ----------------
// Block bi: b = bi&63 (row), q = bi>>6 (output quarter, 128 outputs).
// Wave w = t>>6 covers k in [64w, 64w+64); lane l = t&63 covers outputs {2l,2l+1}.
// One __syncthreads per step (between MAC and epilogue); hL/red parity-buffered.
__global__ __launch_bounds__(512, 2) void rnn_scan_coop(
    float* xw,                        // [B][T][512]
    const float* __restrict__ Whh,    // [512][512] row-major (j,k)
    unsigned long long* hbuf,         // [2][B][512] packed (seq<<32 | bits)
    float* h_final,                   // [B][512] or null
    const int store_seq) {
  const int bi = blockIdx.x;
  const int b = bi & 63;
  const int q = bi >> 6;
  const int t = threadIdx.x;
  const int w = t >> 6;    // wave id, uniform
  const int l = t & 63;
  const int kq = w >> 1;   // k-quarter this wave consumes
  const int half = w & 1;
  const int jg0 = q * 128 + 2 * l;  // global W rows {jg0, jg0+1}

  __shared__ __align__(16) float hL[2][Hdim];
  __shared__ __align__(16) float red[2][8][128];
  __shared__ int ownseq[2];

  // ---- load W slice (2 rows x 64 k) and pin in registers ----
  float4 W0[16], W1[16];
  {
    const float4* w0p = (const float4*)(Whh + (size_t)jg0 * Hdim + w * 64);
    const float4* w1p = (const float4*)(Whh + (size_t)(jg0 + 1) * Hdim + w * 64);
#pragma unroll
    for (int c = 0; c < 16; ++c) {
      W0[c] = w0p[c];
      W1[c] = w1p[c];
    }
  }
#pragma unroll
  for (int c = 0; c < 16; ++c) {
    asm volatile("" : "+v"(W0[c].x), "+v"(W0[c].y), "+v"(W0[c].z), "+v"(W0[c].w));
    asm volatile("" : "+v"(W1[c].x), "+v"(W1[c].y), "+v"(W1[c].z), "+v"(W1[c].w));
  }

  hL[0][t] = 0.0f;  // h_{-1} = 0
  if (t < 2) ownseq[t] = 0;
  __syncthreads();

  float* row = xw + (size_t)b * Tdim * Hdim;
  float xv = (t < 128) ? row[q * 128 + t] : 0.f;  // xw for step 0

  for (int s = 0; s < Tdim; ++s, row += Hdim) {
    const int sp = s & 1;

    // ---- Phase A: acquire this wave's h_{s-1} slice, then MAC ----
    if (s > 0) {
      if (kq == q) {
        // own quarter: written by epilogue(s-1) into hL[sp]; flag carries s
        while (__hip_atomic_load(&ownseq[half], __ATOMIC_ACQUIRE,
                                 __HIP_MEMORY_SCOPE_WORKGROUP) < s) {
        }
      } else {
        // peer quarter: poll the self-flagged word, pull into hL[sp]
        const unsigned long long* src = hbuf +
                                        (size_t)((s - 1) & 1) * (Bdim * Hdim) +
                                        b * Hdim + kq * 128 + half * 64 + l;
        unsigned long long v;
        do {
          v = __hip_atomic_load(src, __ATOMIC_RELAXED, __HIP_MEMORY_SCOPE_AGENT);
        } while ((unsigned)(v >> 32) != (unsigned)s);
        hL[sp][w * 64 + l] = __uint_as_float((unsigned)v);
      }
    }
    const float4* h4 = (const float4*)&hL[sp][w * 64];
    float a0 = 0.f, a0b = 0.f, a1 = 0.f, a1b = 0.f;
#pragma unroll
    for (int c = 0; c < 16; ++c) {
      const float4 hv = h4[c];
      a0  = fmaf(W0[c].x, hv.x, a0);
      a0b = fmaf(W0[c].y, hv.y, a0b);
      a0  = fmaf(W0[c].z, hv.z, a0);
      a0b = fmaf(W0[c].w, hv.w, a0b);
      a1  = fmaf(W1[c].x, hv.x, a1);
      a1b = fmaf(W1[c].y, hv.y, a1b);
      a1  = fmaf(W1[c].z, hv.z, a1);
      a1b = fmaf(W1[c].w, hv.w, a1b);
    }
    *(float2*)&red[sp][w][2 * l] = make_float2(a0 + a0b, a1 + a1b);
    __syncthreads();  // the ONE barrier per step

    // ---- Phase B: epilogue (waves 0-1); other waves flow into next Phase A ----
    if (t < 128) {
      float y = xv;
#pragma unroll
      for (int w8 = 0; w8 < 8; ++w8) y += red[sp][w8][t];
      const float hn = tanhf(y);
      // publish first: it's the critical path for 3 peer CUs
      const unsigned long long pv =
          ((unsigned long long)(unsigned)(s + 1) << 32) |
          (unsigned long long)__float_as_uint(hn);
      __hip_atomic_store(&hbuf[(size_t)sp * (Bdim * Hdim) + b * Hdim + q * 128 + t],
                         pv, __ATOMIC_RELAXED, __HIP_MEMORY_SCOPE_AGENT);
      hL[sp ^ 1][q * 128 + t] = hn;  // own quarter for step s+1
      if (l == 0)  // lane 0 of each epilogue wave: release own wave's hL writes
        __hip_atomic_store(&ownseq[t >> 6], s + 1, __ATOMIC_RELEASE,
                           __HIP_MEMORY_SCOPE_WORKGROUP);
      if (store_seq) row[q * 128 + t] = hn;
      if (s + 1 < Tdim)
        xv = row[Hdim + q * 128 + t];  // prefetch next step's xw
      else if (h_final != nullptr)
        h_final[(size_t)b * Hdim + q * 128 + t] = hn;
    }
  }
}

// ---------------- final FC ----------------
__global__ __launch_bounds__(256) void fc_kernel(const float* __restrict__ h,
                                                 const float* __restrict__ Wfc,
                                                 const float* __restrict__ bfc,
                                                 float* __restrict__ out) {
  __shared__ float hs[Hdim];
  const int b = blockIdx.x, o = threadIdx.x;
  hs[o] = h[(size_t)b * Hdim + o];
  hs[o + 256] = h[(size_t)b * Hdim + 256 + o];
  __syncthreads();
  float acc = bfc[o];
  const float* wr = Wfc + (size_t)o * Hdim;
#pragma unroll 4
  for (int k = 0; k < Hdim; k += 4) {
    const float4 w = *(const float4*)(wr + k);
    acc = fmaf(w.x, hs[k], acc);
    acc = fmaf(w.y, hs[k + 1], acc);
    acc = fmaf(w.z, hs[k + 2], acc);
    acc = fmaf(w.w, hs[k + 3], acc);
  }
  out[(size_t)b * Odim + o] = acc;
}

extern "C" void kernel_launch(void* const* d_in, const int* in_sizes, int n_in,
                              void* d_out, int out_size, void* d_ws, size_t ws_size,
                              hipStream_t stream) {
  const float* x = (const float*)d_in[0];
  const float* W_ih0 = (const float*)d_in[1];
  const float* W_hh0 = (const float*)d_in[2];
  const float* b_ih0 = (const float*)d_in[3];
  const float* b_hh0 = (const float*)d_in[4];
  const float* W_ih1 = (const float*)d_in[5];
  const float* W_hh1 = (const float*)d_in[6];
  const float* b_ih1 = (const float*)d_in[7];
  const float* b_hh1 = (const float*)d_in[8];
  const float* W_fc = (const float*)d_in[9];
  const float* b_fc = (const float*)d_in[10];
  float* out = (float*)d_out;

  float* A = (float*)d_ws;                                     // 134 MB
  unsigned long long* hbuf0 =
      (unsigned long long*)(A + (size_t)Bdim * Tdim * Hdim);   // 512 KB
  unsigned long long* hbuf1 = hbuf0 + (size_t)2 * Bdim * Hdim; // 512 KB
  float* hT1 = (float*)(hbuf1 + (size_t)2 * Bdim * Hdim);      // 128 KB
  // hbuf poison (0xAA..) never matches a valid seq (exact-equality poll);
  // separate per-layer buffers avoid cross-dispatch seq collisions.

  // A = x @ W_ih0^T + b_ih0 + b_hh0
  gemm_rows<Ddim><<<(Bdim * Tdim) / 64, 1024, 0, stream>>>(x, W_ih0, b_ih0, b_hh0, A);

  // layer-0 scan: A <- out0 (in place)
  {
    float* xwp = A;
    const float* W = W_hh0;
    unsigned long long* hb = hbuf0;
    float* hf = nullptr;
    int ss = 1;
    void* args[] = {&xwp, (void*)&W, &hb, &hf, &ss};
    hipLaunchCooperativeKernel((void*)rnn_scan_coop, dim3(Bdim * 4), dim3(512),
                               args, 0, stream);
  }

  // A <- A @ W_ih1^T + b_ih1 + b_hh1 (in place)
  gemm_rows<Hdim><<<(Bdim * Tdim) / 64, 1024, 0, stream>>>(A, W_ih1, b_ih1, b_hh1, A);

  // layer-1 scan: final hidden only
  {
    float* xwp = A;
    const float* W = W_hh1;
    unsigned long long* hb = hbuf1;
    float* hf = hT1;
    int ss = 0;
    void* args[] = {&xwp, (void*)&W, &hb, &hf, &ss};
    hipLaunchCooperativeKernel((void*)rnn_scan_coop, dim3(Bdim * 4), dim3(512),
                               args, 0, stream);
  }

  // out = hT1 @ W_fc^T + b_fc
  fc_kernel<<<Bdim, Odim, 0, stream>>>(hT1, W_fc, b_fc, out);
}

// Round 5
// 3542.550 us; speedup vs baseline: 4.5954x; 1.0222x over previous
//
#include <hip/hip_runtime.h>
#include <cmath>

// MultiLayerRNN: B=64, T=1024, D=256, H=512, O=256, L=2 (all fp32)
//
// R5: role-swapped epilogue. 256 wgs = 64 rows x 4 quarters; W slice pinned in
// regs. Wave w consumes k-slice [64w,64w+64). Epilogue for wg q runs on waves
// 2q,2q+1 (the waves whose MAC inputs are the wg's OWN outputs -> zero-wait
// own-quarter handoff); the 6 peer waves poll packed (seq<<32|bits) words and
// overlap the MALL latency with the producer's epilogue. One barrier/step.
// tanh via exact 1-2/(exp(2y)+1) (v_exp+v_rcp), not ocml tanhf.

#define Bdim 64
#define Tdim 1024
#define Ddim 256
#define Hdim 512
#define Odim 256

// ---------------- row-blocked GEMM: C[m][n] = sum_k A[m][k]*W[n][k] + ba[n] + bb[n]
template <int K>
__global__ __launch_bounds__(1024) void gemm_rows(const float* A, const float* W,
                                                  const float* __restrict__ bias_a,
                                                  const float* __restrict__ bias_b,
                                                  float* C) {
  constexpr int KT = 16;
  __shared__ __align__(16) float As[64][KT];
  __shared__ __align__(16) float Ws[KT][516];
  const int t = threadIdx.x;
  const size_t row0 = (size_t)blockIdx.x * 64;
  const int tn = t & 127;
  const int tm = t >> 7;

  float acc[8][4];
#pragma unroll
  for (int i = 0; i < 8; ++i)
#pragma unroll
    for (int j = 0; j < 4; ++j) acc[i][j] = 0.f;

  const int r_st = t >> 4;
  const int k_st = t & 15;

  for (int k0 = 0; k0 < K; k0 += KT) {
    As[r_st][k_st] = A[(row0 + r_st) * K + k0 + k_st];
#pragma unroll
    for (int rep = 0; rep < 8; ++rep) {
      const int idx = rep * 1024 + t;
      const int n = idx >> 4;
      const int kk = idx & 15;
      Ws[kk][n] = W[(size_t)n * K + k0 + kk];
    }
    __syncthreads();
#pragma unroll
    for (int kk = 0; kk < KT; ++kk) {
      float a[8];
#pragma unroll
      for (int i = 0; i < 8; ++i) a[i] = As[tm * 8 + i][kk];
      const float4 w = *(const float4*)&Ws[kk][tn * 4];
#pragma unroll
      for (int i = 0; i < 8; ++i) {
        acc[i][0] = fmaf(a[i], w.x, acc[i][0]);
        acc[i][1] = fmaf(a[i], w.y, acc[i][1]);
        acc[i][2] = fmaf(a[i], w.z, acc[i][2]);
        acc[i][3] = fmaf(a[i], w.w, acc[i][3]);
      }
    }
    __syncthreads();
  }
  float bn[4];
#pragma unroll
  for (int j = 0; j < 4; ++j) bn[j] = bias_a[tn * 4 + j] + bias_b[tn * 4 + j];
#pragma unroll
  for (int i = 0; i < 8; ++i) {
    float4 v;
    v.x = acc[i][0] + bn[0];
    v.y = acc[i][1] + bn[1];
    v.z = acc[i][2] + bn[2];
    v.w = acc[i][3] + bn[3];
    *(float4*)&C[(row0 + tm * 8 + i) * (size_t)Hdim + tn * 4] = v;
  }
}

__device__ __forceinline__ float fast_tanh(float y) {
  // exact identity: tanh(y) = 1 - 2/(exp(2y)+1); exp->v_exp_f32, rcp->v_rcp_f32.
  // y=+inf -> 1, y=-inf -> -1. |err| ~1e-7, fine vs 1.27e-2 threshold.
  const float e2 = __expf(2.0f * y);
  return 1.0f - 2.0f * __builtin_amdgcn_rcpf(e2 + 1.0f);
}

// ---------------- role-swapped pipelined register-resident scan ----------------
// Block bi: b = bi&63 (row), q = bi>>6 (output quarter, 128 outputs).
// Wave w = t>>6 consumes k in [64w, 64w+64); lane l = t&63 holds W rows
// {q*128+2l, q*128+2l+1} over that k-slice (128 regs, pinned).
// Epilogue waves: w in {2q, 2q+1} (own-quarter consumers). Flat index t is
// simultaneously: k index (consumers), output index (epilogue), hbuf word index.
__global__ __launch_bounds__(512, 2) void rnn_scan_coop(
    float* xw,                        // [B][T][512]
    const float* __restrict__ Whh,    // [512][512] row-major (j,k)
    unsigned long long* hbuf,         // [2][B][512] packed (seq<<32 | bits)
    float* h_final,                   // [B][512] or null
    const int store_seq) {
  const int bi = blockIdx.x;
  const int b = bi & 63;
  const int q = bi >> 6;
  const int t = threadIdx.x;
  const int w = t >> 6;    // wave id, uniform
  const int l = t & 63;
  const int jg0 = q * 128 + 2 * l;       // global W rows {jg0, jg0+1}
  const bool is_epi = ((w >> 1) == q);   // wave-uniform role

  __shared__ __align__(16) float hL[2][Hdim];
  __shared__ __align__(16) float red[2][8][128];

  // ---- load W slice (2 rows x 64 k) and pin in registers ----
  float4 W0[16], W1[16];
  {
    const float4* w0p = (const float4*)(Whh + (size_t)jg0 * Hdim + w * 64);
    const float4* w1p = (const float4*)(Whh + (size_t)(jg0 + 1) * Hdim + w * 64);
#pragma unroll
    for (int c = 0; c < 16; ++c) {
      W0[c] = w0p[c];
      W1[c] = w1p[c];
    }
  }
#pragma unroll
  for (int c = 0; c < 16; ++c) {
    asm volatile("" : "+v"(W0[c].x), "+v"(W0[c].y), "+v"(W0[c].z), "+v"(W0[c].w));
    asm volatile("" : "+v"(W1[c].x), "+v"(W1[c].y), "+v"(W1[c].z), "+v"(W1[c].w));
  }

  hL[0][t] = 0.0f;  // h_{-1} = 0
  __syncthreads();

  float* row = xw + (size_t)b * Tdim * Hdim;
  unsigned long long* hb_row = hbuf + b * Hdim;          // parity 0 base
  float xv = is_epi ? row[t] : 0.f;                      // xw for step 0

  for (int s = 0; s < Tdim; ++s, row += Hdim) {
    const int sp = s & 1;

    // ---- acquire this wave's h_{s-1} k-slice ----
    if (s > 0 && !is_epi) {
      // peer quarter: poll the self-flagged word written by wg (w>>1)
      const unsigned long long* src =
          hb_row + (size_t)((s - 1) & 1) * (Bdim * Hdim) + t;
      unsigned long long v;
      do {
        v = __hip_atomic_load(src, __ATOMIC_RELAXED, __HIP_MEMORY_SCOPE_AGENT);
      } while ((unsigned)(v >> 32) != (unsigned)s);
      hL[sp][t] = __uint_as_float((unsigned)v);
    }
    // epilogue waves: hL[sp][64w..64w+64) was written by THIS wave at s-1 (or init)

    // ---- MAC over k-slice [64w, 64w+64) (wave-uniform LDS broadcasts) ----
    const float4* h4 = (const float4*)&hL[sp][w * 64];
    float a0 = 0.f, a0b = 0.f, a1 = 0.f, a1b = 0.f;
#pragma unroll
    for (int c = 0; c < 16; ++c) {
      const float4 hv = h4[c];
      a0  = fmaf(W0[c].x, hv.x, a0);
      a0b = fmaf(W0[c].y, hv.y, a0b);
      a0  = fmaf(W0[c].z, hv.z, a0);
      a0b = fmaf(W0[c].w, hv.w, a0b);
      a1  = fmaf(W1[c].x, hv.x, a1);
      a1b = fmaf(W1[c].y, hv.y, a1b);
      a1  = fmaf(W1[c].z, hv.z, a1);
      a1b = fmaf(W1[c].w, hv.w, a1b);
    }
    *(float2*)&red[sp][w][2 * l] = make_float2(a0 + a0b, a1 + a1b);
    __syncthreads();  // the ONE barrier per step

    // ---- epilogue on own-quarter waves; peer waves flow into next poll ----
    if (is_epi) {
      const int e = t & 127;  // output index within quarter; global j == t
      float y = xv;
#pragma unroll
      for (int w8 = 0; w8 < 8; ++w8) y += red[sp][w8][e];
      const float hn = fast_tanh(y);
      // publish first: it's the critical path for the 3 peer CUs
      const unsigned long long pv =
          ((unsigned long long)(unsigned)(s + 1) << 32) |
          (unsigned long long)__float_as_uint(hn);
      __hip_atomic_store(hb_row + (size_t)sp * (Bdim * Hdim) + t, pv,
                         __ATOMIC_RELAXED, __HIP_MEMORY_SCOPE_AGENT);
      hL[sp ^ 1][t] = hn;  // own k-slice for step s+1 (same-wave write->read)
      if (store_seq) row[t] = hn;
      if (s + 1 < Tdim)
        xv = row[Hdim + t];  // prefetch next step's xw
      else if (h_final != nullptr)
        h_final[(size_t)b * Hdim + t] = hn;
    }
  }
}

// ---------------- final FC ----------------
__global__ __launch_bounds__(256) void fc_kernel(const float* __restrict__ h,
                                                 const float* __restrict__ Wfc,
                                                 const float* __restrict__ bfc,
                                                 float* __restrict__ out) {
  __shared__ float hs[Hdim];
  const int b = blockIdx.x, o = threadIdx.x;
  hs[o] = h[(size_t)b * Hdim + o];
  hs[o + 256] = h[(size_t)b * Hdim + 256 + o];
  __syncthreads();
  float acc = bfc[o];
  const float* wr = Wfc + (size_t)o * Hdim;
#pragma unroll 4
  for (int k = 0; k < Hdim; k += 4) {
    const float4 w = *(const float4*)(wr + k);
    acc = fmaf(w.x, hs[k], acc);
    acc = fmaf(w.y, hs[k + 1], acc);
    acc = fmaf(w.z, hs[k + 2], acc);
    acc = fmaf(w.w, hs[k + 3], acc);
  }
  out[(size_t)b * Odim + o] = acc;
}

extern "C" void kernel_launch(void* const* d_in, const int* in_sizes, int n_in,
                              void* d_out, int out_size, void* d_ws, size_t ws_size,
                              hipStream_t stream) {
  const float* x = (const float*)d_in[0];
  const float* W_ih0 = (const float*)d_in[1];
  const float* W_hh0 = (const float*)d_in[2];
  const float* b_ih0 = (const float*)d_in[3];
  const float* b_hh0 = (const float*)d_in[4];
  const float* W_ih1 = (const float*)d_in[5];
  const float* W_hh1 = (const float*)d_in[6];
  const float* b_ih1 = (const float*)d_in[7];
  const float* b_hh1 = (const float*)d_in[8];
  const float* W_fc = (const float*)d_in[9];
  const float* b_fc = (const float*)d_in[10];
  float* out = (float*)d_out;

  float* A = (float*)d_ws;                                     // 134 MB
  unsigned long long* hbuf0 =
      (unsigned long long*)(A + (size_t)Bdim * Tdim * Hdim);   // 512 KB
  unsigned long long* hbuf1 = hbuf0 + (size_t)2 * Bdim * Hdim; // 512 KB
  float* hT1 = (float*)(hbuf1 + (size_t)2 * Bdim * Hdim);      // 128 KB
  // hbuf poison (0xAA..) never matches a valid seq (exact-equality poll);
  // separate per-layer buffers avoid cross-dispatch seq collisions.

  // A = x @ W_ih0^T + b_ih0 + b_hh0
  gemm_rows<Ddim><<<(Bdim * Tdim) / 64, 1024, 0, stream>>>(x, W_ih0, b_ih0, b_hh0, A);

  // layer-0 scan: A <- out0 (in place)
  {
    float* xwp = A;
    const float* W = W_hh0;
    unsigned long long* hb = hbuf0;
    float* hf = nullptr;
    int ss = 1;
    void* args[] = {&xwp, (void*)&W, &hb, &hf, &ss};
    hipLaunchCooperativeKernel((void*)rnn_scan_coop, dim3(Bdim * 4), dim3(512),
                               args, 0, stream);
  }

  // A <- A @ W_ih1^T + b_ih1 + b_hh1 (in place)
  gemm_rows<Hdim><<<(Bdim * Tdim) / 64, 1024, 0, stream>>>(A, W_ih1, b_ih1, b_hh1, A);

  // layer-1 scan: final hidden only
  {
    float* xwp = A;
    const float* W = W_hh1;
    unsigned long long* hb = hbuf1;
    float* hf = hT1;
    int ss = 0;
    void* args[] = {&xwp, (void*)&W, &hb, &hf, &ss};
    hipLaunchCooperativeKernel((void*)rnn_scan_coop, dim3(Bdim * 4), dim3(512),
                               args, 0, stream);
  }

  // out = hT1 @ W_fc^T + b_fc
  fc_kernel<<<Bdim, Odim, 0, stream>>>(hT1, W_fc, b_fc, out);
}